// Round 14
// baseline (600.235 us; speedup 1.0000x reference)
//
#include <hip/hip_runtime.h>

typedef unsigned short u16;
typedef unsigned int u32;
typedef unsigned long long u64;
typedef __attribute__((ext_vector_type(8))) short short8;
typedef __attribute__((ext_vector_type(4))) float f32x4;

#define NB_ 64
#define NHELP_ 5096   // 7*(512 copy + 157 gnew256) + (256 copy + 157 gnew128)

static __device__ __forceinline__ f32x4 mfma16(short8 a, short8 b, f32x4 c) {
  return __builtin_amdgcn_mfma_f32_16x16x32_bf16(a, b, c, 0, 0, 0);
}

// split fp32 -> bf16 hi + bf16 lo  (x ~= hi + lo, residual ~2^-17 * |x|)
static __device__ __forceinline__ void split_bf16(float x, u16& hi, u16& lo) {
  unsigned u = __float_as_uint(x);
  unsigned r = (u + 0x7fffu + ((u >> 16) & 1u)) >> 16;
  hi = (u16)r;
  float fh = __uint_as_float(r << 16);
  float xl = x - fh;
  unsigned ul = __float_as_uint(xl);
  unsigned rl2 = (ul + 0x7fffu + ((ul >> 16) & 1u)) >> 16;
  lo = (u16)rl2;
}

// write-through publication store to the coherence point (proven r1-r13)
static __device__ __forceinline__ void astore(u32* p, u32 v) {
  __hip_atomic_store(p, v, __ATOMIC_RELAXED, __HIP_MEMORY_SCOPE_AGENT);
}
static __device__ __forceinline__ void unpack8(const uint4& a, const uint4& b,
                                               short8& h, short8& l) {
  u32 wb[8] = {a.x, a.y, a.z, a.w, b.x, b.y, b.z, b.w};
  #pragma unroll
  for (int j = 0; j < 8; ++j) {
    h[j] = (short)(wb[j] & 0xffffu);
    l[j] = (short)(wb[j] >> 16);
  }
}
static __device__ __forceinline__ float unpack_hl(u32 pk) {
  return __uint_as_float((pk & 0xffffu) << 16) + __uint_as_float(pk & 0xffff0000u);
}
static __device__ __forceinline__ void vload8(const u32* p, short8& h, short8& l) {
  uint4 a = *(const uint4*)p;
  uint4 b = *(const uint4*)(p + 4);
  unpack8(a, b, h, l);
}

// ---------------- prep: pooling (blocks 0..1919) + weight swizzle (1920..5455) ----------------
__global__ __launch_bounds__(256) void k_prep(const int* __restrict__ iv,
                                              const float* __restrict__ emb,
                                              u16* __restrict__ ebh, u16* __restrict__ ebl,
                                              float* __restrict__ cm,
                                              const float* __restrict__ Wih,
                                              const float* __restrict__ Whh,
                                              const float* __restrict__ mWih,
                                              const float* __restrict__ mWhh,
                                              const float* __restrict__ Wnew,
                                              u16* __restrict__ w1h, u16* __restrict__ w1l,
                                              u16* __restrict__ w2h, u16* __restrict__ w2l,
                                              u16* __restrict__ wnh, u16* __restrict__ wnl) {
  if (blockIdx.x < 1920) {
    int u = blockIdx.x * 2 + (threadIdx.x >> 7);   // u = (s*2+t)*64+b
    int s = u >> 7;
    int t = (u >> 6) & 1;
    int b = u & 63;
    int d = threadIdx.x & 127;
    const int ibase = ((t * 64 + b) * 30 + s) * 12;
    float sum = 0.f;
    int cnt = 0;
    for (int k = 0; k < 12; ++k) {
      int idx = iv[ibase + k];
      if (idx > 0) { cnt++; sum += emb[(size_t)idx * 128 + d]; }
    }
    float den = (cnt > 0) ? (float)cnt : 1.f;
    float v = sum / den;
    u16 hi, lo; split_bf16(v, hi, lo);
    ebh[(size_t)u * 128 + d] = hi;
    ebl[(size_t)u * 128 + d] = lo;
    if (d == 0) cm[u] = (cnt > 0) ? 1.f : 0.f;
    return;
  }
  int gu = (blockIdx.x - 1920) * 4 + (threadIdx.x >> 6);
  int lane = threadIdx.x & 63;
  int ko = (lane >> 4) * 8;
  int cl = lane & 15;
  float src[8];
  if (gu < 2560) {
    int blk = gu / 40, r = gu % 40, ksIdx = r >> 1, nt = r & 1;
    int t = blk >> 5, hd0 = (blk & 31) * 8;
    int c = nt * 16 + cl;
    if (c < 24) {
      int gc = (c < 8) ? (hd0 + c) : (c < 16) ? (256 + hd0 + (c - 8)) : (512 + hd0 + (c - 16));
      const float* wrow; int kk;
      if (ksIdx < 8)       { wrow = Wih + (size_t)(t * 768 + gc) * 384 + 128; kk = ksIdx * 32 + ko; }
      else if (ksIdx < 16) { wrow = Whh + (size_t)(t * 768 + gc) * 256;       kk = (ksIdx - 8) * 32 + ko; }
      else                 { wrow = Wih + (size_t)(t * 768 + gc) * 384;       kk = (ksIdx - 16) * 32 + ko; }
      #pragma unroll
      for (int j = 0; j < 8; ++j) src[j] = wrow[kk + j];
    } else {
      #pragma unroll
      for (int j = 0; j < 8; ++j) src[j] = 0.f;
    }
    int off = gu * 512 + lane * 8;
    #pragma unroll
    for (int j = 0; j < 8; ++j) { u16 h, l; split_bf16(src[j], h, l); w1h[off + j] = h; w1l[off + j] = l; }
  } else if (gu < 4096) {
    int g2 = gu - 2560;
    int blk = g2 / 24, ksIdx = g2 % 24;
    int t1 = blk >> 5;
    int hd0 = blk * 4;
    int c = cl;
    if (c < 12) {
      int gc = (c < 4) ? (hd0 + c) : (c < 8) ? (256 + hd0 + (c - 4)) : (512 + hd0 + (c - 8));
      if (ksIdx < 16) {
        int chunk = (ksIdx < 8) ? (t1 * 8 + ksIdx) : ((1 - t1) * 8 + (ksIdx - 8));
        int kk = chunk * 32 + ko;
        #pragma unroll
        for (int j = 0; j < 8; ++j) src[j] = mWih[(size_t)gc * 512 + kk + j];
      } else {
        int kk = (ksIdx - 16) * 32 + ko;
        #pragma unroll
        for (int j = 0; j < 8; ++j) src[j] = mWhh[(size_t)gc * 256 + kk + j];
      }
    } else {
      #pragma unroll
      for (int j = 0; j < 8; ++j) src[j] = 0.f;
    }
    int off = g2 * 512 + lane * 8;
    #pragma unroll
    for (int j = 0; j < 8; ++j) { u16 h, l; split_bf16(src[j], h, l); w2h[off + j] = h; w2l[off + j] = l; }
  } else if (gu < 14144) {
    int g3 = gu - 4096;
    int gnt = g3 >> 3, ks = g3 & 7;
    int col = gnt * 16 + cl;
    if (col < 20000) {
      int kk = ks * 32 + ko;
      #pragma unroll
      for (int j = 0; j < 8; ++j) src[j] = Wnew[(size_t)col * 256 + kk + j];
    } else {
      #pragma unroll
      for (int j = 0; j < 8; ++j) src[j] = 0.f;
    }
    int off = g3 * 512 + lane * 8;
    #pragma unroll
    for (int j = 0; j < 8; ++j) { u16 h, l; split_bf16(src[j], h, l); wnh[off + j] = h; wnl[off + j] = l; }
  }
}

// ---------------- gi_x precompute: gi_x = x @ WihX^T (+bias folds) ----------------
__global__ __launch_bounds__(256) void k_gix(const u16* __restrict__ ebh, const u16* __restrict__ ebl,
                                             const u16* __restrict__ w1h, const u16* __restrict__ w1l,
                                             const float* __restrict__ bih, const float* __restrict__ bhh,
                                             float* __restrict__ gix) {
  int blk = blockIdx.x;
  int t1 = blk >> 5, hd1 = (blk & 31) * 8;
  int tid = threadIdx.x, lane = tid & 63, w = tid >> 6;
  int arow = w * 16 + (lane & 15);
  int ko = (lane >> 4) * 8;
  __shared__ u16 lwh[4096], lwl[4096];
  {
    const uint4* sh = (const uint4*)(w1h + ((size_t)blk * 40 + 32) * 512);
    const uint4* sl = (const uint4*)(w1l + ((size_t)blk * 40 + 32) * 512);
    uint4* dh = (uint4*)lwh; uint4* dl = (uint4*)lwl;
    for (int i = tid; i < 512; i += 256) { dh[i] = sh[i]; dl[i] = sl[i]; }
  }
  int c = lane & 15;
  float brz, bn = 0.f;
  {
    int gc = (c < 8) ? (hd1 + c) : (256 + hd1 + (c - 8));
    brz = bih[t1 * 768 + gc] + bhh[t1 * 768 + gc];
    if (c < 8) bn = bih[t1 * 768 + 512 + hd1 + c];
  }
  __syncthreads();
  for (int s = 0; s < 30; ++s) {
    f32x4 a3[2];
    a3[0] = (f32x4){0.f, 0.f, 0.f, 0.f};
    a3[1] = (f32x4){0.f, 0.f, 0.f, 0.f};
    const u16* Xh = ebh + (size_t)((s * 2 + t1) * 64 + arow) * 128;
    const u16* Xl = ebl + (size_t)((s * 2 + t1) * 64 + arow) * 128;
    #pragma unroll
    for (int k = 0; k < 4; ++k) {
      short8 xh = *(const short8*)(Xh + k * 32 + ko);
      short8 xl = *(const short8*)(Xl + k * 32 + ko);
      #pragma unroll
      for (int nt = 0; nt < 2; ++nt) {
        short8 bh = *(const short8*)(lwh + (k * 2 + nt) * 512 + lane * 8);
        short8 bl = *(const short8*)(lwl + (k * 2 + nt) * 512 + lane * 8);
        a3[nt] = mfma16(xh, bh, a3[nt]);
        a3[nt] = mfma16(xl, bh, a3[nt]);
        a3[nt] = mfma16(xh, bl, a3[nt]);
      }
    }
    float* grow = gix + (size_t)(blk * 30 + s) * 64 * 32;
    #pragma unroll
    for (int i = 0; i < 4; ++i) {
      int r = w * 16 + (lane >> 4) * 4 + i;
      grow[r * 32 + c] = a3[0][i] + brz;
      if (c < 8) grow[r * 32 + 16 + c] = a3[1][i] + bn;
    }
  }
}

// ---------------- barrier helpers ----------------
static __device__ __forceinline__ void bar_arrive(u32* slots, int blk, int epoch) {
  __syncthreads();              // all waves' publication stores drained
  if (threadIdx.x == 0) astore(slots + blk, (u32)epoch);
}
static __device__ __forceinline__ void bar_wait(u32* slots, int epoch) {
  int lane = threadIdx.x & 63;
  u32 v;
  for (;;) {
    asm volatile("global_load_dword %0, %1, off sc0 sc1\n\ts_waitcnt vmcnt(0)"
                 : "=v"(v) : "v"(slots + lane) : "memory");
    if ((int)v >= epoch) break;
  }
}
// helpers poll ONLY hprog (own cache line, written by rnn block 0)
static __device__ __forceinline__ void helper_wait(const u32* hprog, int target) {
  if (threadIdx.x == 0) {
    u32 v;
    for (;;) {
      asm volatile("global_load_dword %0, %1, off sc0 sc1\n\ts_waitcnt vmcnt(0)"
                   : "=v"(v) : "v"(hprog) : "memory");
      if ((int)v >= target) break;
      __builtin_amdgcn_s_sleep(15);
      __builtin_amdgcn_s_sleep(15);
    }
  }
  __syncthreads();
}

// gnew tile: MI m-subtiles of 16 rows per wave (rows = 64*MI per block)
// wn operands + out stores are NON-TEMPORAL: no reuse -> keep them out of L2
// so the rnn blocks' hpk/apk lines stay resident.
template<int MI>
static __device__ __forceinline__ void gnew_tile(int rowbase, int nb, int tid,
                                                 const u32* __restrict__ apk,
                                                 const u16* __restrict__ wnh,
                                                 const u16* __restrict__ wnl,
                                                 const float* __restrict__ bnew,
                                                 float* __restrict__ out) {
  int lane = tid & 63, w = tid >> 6;
  int ko = (lane >> 4) * 8;
  f32x4 acc[MI][8];
  #pragma unroll
  for (int mi = 0; mi < MI; ++mi)
    #pragma unroll
    for (int nt = 0; nt < 8; ++nt) acc[mi][nt] = (f32x4){0.f, 0.f, 0.f, 0.f};
  #pragma unroll
  for (int ks = 0; ks < 8; ++ks) {
    short8 ah[MI], al[MI];
    #pragma unroll
    for (int mi = 0; mi < MI; ++mi) {
      int rrow = rowbase + (w * MI + mi) * 16 + (lane & 15);
      vload8(apk + (size_t)rrow * 256 + ks * 32 + ko, ah[mi], al[mi]);
    }
    #pragma unroll
    for (int nt = 0; nt < 8; ++nt) {
      int un = (nb * 8 + nt) * 8 + ks;
      short8 bh = __builtin_nontemporal_load((const short8*)(wnh + (size_t)un * 512 + lane * 8));
      short8 bl = __builtin_nontemporal_load((const short8*)(wnl + (size_t)un * 512 + lane * 8));
      #pragma unroll
      for (int mi = 0; mi < MI; ++mi) {
        acc[mi][nt] = mfma16(ah[mi], bh, acc[mi][nt]);
        acc[mi][nt] = mfma16(al[mi], bh, acc[mi][nt]);
        acc[mi][nt] = mfma16(ah[mi], bl, acc[mi][nt]);
      }
    }
  }
  #pragma unroll
  for (int mi = 0; mi < MI; ++mi)
    #pragma unroll
    for (int nt = 0; nt < 8; ++nt) {
      int col = nb * 128 + nt * 16 + (lane & 15);
      if (col < 20000) {
        float bn = bnew[col];
        #pragma unroll
        for (int i = 0; i < 4; ++i) {
          int rrow = rowbase + (w * MI + mi) * 16 + (lane >> 4) * 4 + i;
          int sA = rrow >> 6, bA = rrow & 63;
          __builtin_nontemporal_store(acc[mi][nt][i] + bn,
                                      out + (size_t)(bA * 30 + sA) * 20000 + col);
        }
      }
    }
}

// dynamic LDS layout (bytes):
//   [0) w1h 32768 | w1l 32768 | w2h 24576 | w2l 24576 | ls_rz 4096 | ls_gi 2048
//   | ls_gh 2048 | ls_cm 7680 -> total 130560
#define RNN_LDS 130560

// Mega kernel: blocks 0..63 = persistent GRU recurrence (apk s-major);
// helpers ordered by readiness: g=0..6: {512 copy (s=4g..4g+3), 157 gnew256 q=g};
// then {256 copy (s=28,29), 157 gnew128 q=7}.
__global__ __launch_bounds__(256, 1) void k_mega(
    const u16* __restrict__ w1h, const u16* __restrict__ w1l,
    const u16* __restrict__ w2h, const u16* __restrict__ w2l,
    const float* __restrict__ gix,
    const float* __restrict__ bhh,
    const float* __restrict__ mbih, const float* __restrict__ mbhh,
    const float* __restrict__ cm,
    u32* __restrict__ hpk,       // packed (hi|lo<<16) task-h   [31][2][64][256]
    u32* __restrict__ apk,       // packed (hi|lo<<16) meta-h   [30][64][256]  (s-major)
    u32* slots,                  // [0..63] rnn flags; [64] hprog (own line)
    const u16* __restrict__ wnh, const u16* __restrict__ wnl,
    const float* __restrict__ bnew,
    const int* __restrict__ cv,
    const float* __restrict__ wc,
    const float* __restrict__ bc,
    float* __restrict__ out) {
  u32* hprog = slots + 64;

  if (blockIdx.x >= NB_) {
    // ================= helper blocks =================
    int h = blockIdx.x - NB_;
    int tid = threadIdx.x, lane = tid & 63, w = tid >> 6;
    int s = -1, rr = 0, q = -1, nb = 0;
    if (h < 4683) {
      int g = h / 669, r = h % 669;
      if (r < 512) { s = 4 * g + (r >> 7); rr = r & 127; }
      else         { q = g; nb = r - 512; }
    } else {
      int h2 = h - 4683;
      if (h2 < 256) { s = 28 + (h2 >> 7); rr = h2 & 127; }
      else          { q = 7; nb = h2 - 256; }
    }
    if (s >= 0) {
      // ---- copy-score block: zero own row early (nt), wait, scatter ----
      int t = rr >> 6, b = rr & 63;
      float* orow = out + (size_t)(1 + t) * 38400000 + (size_t)(b * 30 + s) * 20000;
      f32x4 z4 = {0.f, 0.f, 0.f, 0.f};
      f32x4* zp = (f32x4*)orow;
      for (int i = tid; i < 5000; i += 256)
        __builtin_nontemporal_store(z4, zp + i);
      helper_wait(hprog, 2 * s + 1);   // syncthreads inside drains zero-stores
      const u32* hp = hpk + (size_t)(((s + 1) * 2 + t) * 64 + b) * 256;
      uint4 hq = *(const uint4*)(hp + lane * 4);
      float4 h4;
      h4.x = unpack_hl(hq.x); h4.y = unpack_hl(hq.y);
      h4.z = unpack_hl(hq.z); h4.w = unpack_hl(hq.w);
      int base = ((t * 64 + b) * 30 + s) * 20;
      for (int c = w; c < 20; c += 4) {
        int idx = cv[base + c];
        const float* wr = wc + ((size_t)t * 20000 + idx) * 256;
        f32x4 w4 = __builtin_nontemporal_load((const f32x4*)(wr + lane * 4));
        float d = h4.x * w4.x + h4.y * w4.y + h4.z * w4.z + h4.w * w4.w;
        #pragma unroll
        for (int m = 32; m >= 1; m >>= 1) d += __shfl_xor(d, m, 64);
        if (lane == 0) orow[idx] = d + bc[t * 20000 + idx];
      }
    } else if (q < 7) {
      helper_wait(hprog, 8 * q + 8);   // apk rows s=4q..4q+3 published
      gnew_tile<4>(q * 256, nb, tid, apk, wnh, wnl, bnew, out);
    } else {
      helper_wait(hprog, 60);          // last 128 rows (s=28,29)
      gnew_tile<2>(1792, nb, tid, apk, wnh, wnl, bnew, out);
    }
    return;
  }

  // ================= recurrence blocks (r9/r11 structure) =================
  extern __shared__ char smem[];
  u16* lw1h = (u16*)smem;
  u16* lw1l = (u16*)(smem + 32768);
  u16* lw2h = (u16*)(smem + 65536);
  u16* lw2l = (u16*)(smem + 90112);
  float* ls_rz = (float*)(smem + 114688);
  float* ls_gi = (float*)(smem + 118784);
  float* ls_gh = (float*)(smem + 120832);
  float* ls_cm = (float*)(smem + 122880);

  const int blk = blockIdx.x;
  const int tid = threadIdx.x;
  const int lane = tid & 63;
  const int w = tid >> 6;
  const int t1 = blk >> 5;
  const int hd1 = (blk & 31) * 8;
  const int hd2 = blk * 4;
  const int arow = w * 16 + (lane & 15);
  const int ko = (lane >> 4) * 8;
  int epoch = 0;

  // one-time: weights -> LDS, cm -> LDS
  {
    const uint4* s1h = (const uint4*)(w1h + (size_t)blk * 40 * 512);
    const uint4* s1l = (const uint4*)(w1l + (size_t)blk * 40 * 512);
    uint4* d1h = (uint4*)lw1h; uint4* d1l = (uint4*)lw1l;
    for (int i = tid; i < 2048; i += 256) { d1h[i] = s1h[i]; d1l[i] = s1l[i]; }
    const uint4* s2h = (const uint4*)(w2h + (size_t)blk * 24 * 512);
    const uint4* s2l = (const uint4*)(w2l + (size_t)blk * 24 * 512);
    uint4* d2h = (uint4*)lw2h; uint4* d2l = (uint4*)lw2l;
    for (int i = tid; i < 1536; i += 256) { d2h[i] = s2h[i]; d2l[i] = s2l[i]; }
    for (int i = tid; i < 1920; i += 256) ls_cm[i] = cm[((i >> 6) * 2 + t1) * 64 + (i & 63)];
  }
  // hoisted per-thread constants
  const int cc = lane & 15;
  float bhhn = (cc < 8) ? bhh[t1 * 768 + 512 + hd1 + cc] : 0.f;
  float mrz_b = 0.f, mgi_b = 0.f, mgh_b = 0.f;
  if (cc < 8) {
    int gc = (cc < 4) ? (hd2 + cc) : (256 + hd2 + (cc - 4));
    mrz_b = mbih[gc] + mbhh[gc];
  } else if (cc < 12) {
    int gn = 512 + hd2 + (cc - 8);
    mgi_b = mbih[gn];
    mgh_b = mbhh[gn];
  }

  // gi_x prefetch registers
  float gq[8];
  {
    const float* grow = gix + (size_t)(blk * 30 + 0) * 2048;
    #pragma unroll
    for (int i = 0; i < 4; ++i) {
      int r = w * 16 + (lane >> 4) * 4 + i;
      gq[i]     = grow[r * 32 + cc];
      gq[4 + i] = grow[r * 32 + 16 + (cc & 7)];
    }
  }
  __syncthreads();

  short8 ah1[8], al1[8];   // apk[s-1] (G1; reused by m2)
  short8 xh2[8], xl2[8];   // own-task hpk[s] (loaded phase-2 of s-1; used by a2s)
  f32x4 a2s[2];            // Whh @ h_task, precomputed at end of previous iteration
  a2s[0] = (f32x4){0.f, 0.f, 0.f, 0.f};
  a2s[1] = (f32x4){0.f, 0.f, 0.f, 0.f};
  float hold0 = 0.f, hold1 = 0.f;
  float hm_reg = 0.f;

  for (int s = 0; s < 30; ++s) {
    // ---------- phase 1: task GRUs ----------
    f32x4 a1[2];
    a1[0] = (f32x4){0.f, 0.f, 0.f, 0.f};
    a1[1] = (f32x4){0.f, 0.f, 0.f, 0.f};
    if (s > 0) {
      bar_wait(slots, epoch);
      if (blk == 0 && tid == 0) astore(hprog, (u32)epoch);   // all-arrived(epoch) proven
      const u32* Ap = apk + (size_t)((s - 1) * 64 + arow) * 256 + ko;
      uint4 ra[16];
      #pragma unroll
      for (int k = 0; k < 8; ++k) {
        ra[2 * k]     = *(const uint4*)(Ap + k * 32);
        ra[2 * k + 1] = *(const uint4*)(Ap + k * 32 + 4);
      }
      #pragma unroll
      for (int k = 0; k < 8; ++k) {
        unpack8(ra[2 * k], ra[2 * k + 1], ah1[k], al1[k]);
        #pragma unroll
        for (int nt = 0; nt < 2; ++nt) {
          short8 bh = *(const short8*)(lw1h + (k * 2 + nt) * 512 + lane * 8);
          short8 bl = *(const short8*)(lw1l + (k * 2 + nt) * 512 + lane * 8);
          a1[nt] = mfma16(ah1[k], bh, a1[nt]);
          a1[nt] = mfma16(al1[k], bh, a1[nt]);
          a1[nt] = mfma16(ah1[k], bl, a1[nt]);
        }
      }
    }
    // gates -> LDS (per-wave slices; intra-wave ordering via lgkmcnt)
    #pragma unroll
    for (int i = 0; i < 4; ++i) {
      int rl = (lane >> 4) * 4 + i;
      ls_rz[(w * 16 + rl) * 16 + cc] = a1[0][i] + a2s[0][i] + gq[i];
      if (cc < 8) {
        ls_gi[(w * 16 + rl) * 8 + cc] = a1[1][i] + gq[4 + i];
        ls_gh[(w * 16 + rl) * 8 + cc] = a2s[1][i] + bhhn;
      }
    }
    asm volatile("s_waitcnt lgkmcnt(0)" ::: "memory");
    {
      int item = lane;
      int rl = item >> 3, c = item & 7;
      float rv = ls_rz[(w * 16 + rl) * 16 + c], zv = ls_rz[(w * 16 + rl) * 16 + 8 + c];
      float gi = ls_gi[(w * 16 + rl) * 8 + c], gh = ls_gh[(w * 16 + rl) * 8 + c];
      float r = 1.f / (1.f + expf(-rv));
      float z = 1.f / (1.f + expf(-zv));
      float n = tanhf(gi + r * gh);
      int b = w * 16 + rl;
      float m = ls_cm[s * 64 + b];
      float hnew = (1.f - z) * n + z * hold0;
      float hout = (m > 0.5f) ? hnew : hold0;
      hold0 = hout;
      int oo = (((s + 1) * 2 + t1) * 64 + b) * 256 + hd1 + c;
      u16 xh, xl; split_bf16(hout, xh, xl);
      astore(hpk + oo, (u32)xh | ((u32)xl << 16));
    }
    {
      int item = 64 + lane;
      int rl = item >> 3, c = item & 7;
      float rv = ls_rz[(w * 16 + rl) * 16 + c], zv = ls_rz[(w * 16 + rl) * 16 + 8 + c];
      float gi = ls_gi[(w * 16 + rl) * 8 + c], gh = ls_gh[(w * 16 + rl) * 8 + c];
      float r = 1.f / (1.f + expf(-rv));
      float z = 1.f / (1.f + expf(-zv));
      float n = tanhf(gi + r * gh);
      int b = w * 16 + rl;
      float m = ls_cm[s * 64 + b];
      float hnew = (1.f - z) * n + z * hold1;
      float hout = (m > 0.5f) ? hnew : hold1;
      hold1 = hout;
      int oo = (((s + 1) * 2 + t1) * 64 + b) * 256 + hd1 + c;
      u16 xh, xl; split_bf16(hout, xh, xl);
      astore(hpk + oo, (u32)xh | ((u32)xl << 16));
    }
    ++epoch;
    bar_arrive(slots, blk, epoch);

    // ---- pre-poll local work: m2 (mWhh @ h_meta, regs) + gix prefetch ----
    f32x4 m1 = (f32x4){0.f, 0.f, 0.f, 0.f};
    f32x4 m2 = (f32x4){0.f, 0.f, 0.f, 0.f};
    if (s > 0) {
      #pragma unroll
      for (int k = 0; k < 8; ++k) {
        short8 bh = *(const short8*)(lw2h + (16 + k) * 512 + lane * 8);
        short8 bl = *(const short8*)(lw2l + (16 + k) * 512 + lane * 8);
        m2 = mfma16(ah1[k], bh, m2);
        m2 = mfma16(al1[k], bh, m2);
        m2 = mfma16(ah1[k], bl, m2);
      }
    }
    if (s < 29) {
      const float* grow = gix + (size_t)(blk * 30 + s + 1) * 2048;
      #pragma unroll
      for (int i = 0; i < 4; ++i) {
        int r = w * 16 + (lane >> 4) * 4 + i;
        gq[i]     = grow[r * 32 + cc];
        gq[4 + i] = grow[r * 32 + 16 + (cc & 7)];
      }
    }
    bar_wait(slots, epoch);
    if (blk == 0 && tid == 0) astore(hprog, (u32)epoch);

    // ---------- phase 2: meta GRU ----------
    {
      const u32* Hp = hpk + (size_t)(((s + 1) * 2 + t1) * 64 + arow) * 256 + ko;
      const u32* Hq = hpk + (size_t)(((s + 1) * 2 + (1 - t1)) * 64 + arow) * 256 + ko;
      uint4 rx[16], ry[16];
      #pragma unroll
      for (int k = 0; k < 8; ++k) {
        rx[2 * k]     = *(const uint4*)(Hp + k * 32);
        rx[2 * k + 1] = *(const uint4*)(Hp + k * 32 + 4);
        ry[2 * k]     = *(const uint4*)(Hq + k * 32);
        ry[2 * k + 1] = *(const uint4*)(Hq + k * 32 + 4);
      }
      #pragma unroll
      for (int k = 0; k < 8; ++k) {
        unpack8(rx[2 * k], rx[2 * k + 1], xh2[k], xl2[k]);
        short8 bh = *(const short8*)(lw2h + k * 512 + lane * 8);
        short8 bl = *(const short8*)(lw2l + k * 512 + lane * 8);
        m1 = mfma16(xh2[k], bh, m1);
        m1 = mfma16(xl2[k], bh, m1);
        m1 = mfma16(xh2[k], bl, m1);
      }
      #pragma unroll
      for (int k = 0; k < 8; ++k) {
        short8 yh, yl;
        unpack8(ry[2 * k], ry[2 * k + 1], yh, yl);
        short8 bh = *(const short8*)(lw2h + (8 + k) * 512 + lane * 8);
        short8 bl = *(const short8*)(lw2l + (8 + k) * 512 + lane * 8);
        m1 = mfma16(yh, bh, m1);
        m1 = mfma16(yl, bh, m1);
        m1 = mfma16(yh, bl, m1);
      }
    }
    #pragma unroll
    for (int i = 0; i < 4; ++i) {
      int rl = (lane >> 4) * 4 + i;
      if (cc < 8) {
        ls_rz[(w * 16 + rl) * 16 + cc] = m1[i] + m2[i] + mrz_b;
      } else if (cc < 12) {
        ls_gi[(w * 16 + rl) * 8 + (cc - 8)] = m1[i] + mgi_b;
        ls_gh[(w * 16 + rl) * 8 + (cc - 8)] = m2[i] + mgh_b;
      }
    }
    asm volatile("s_waitcnt lgkmcnt(0)" ::: "memory");
    {
      int rl = lane >> 2, c = lane & 3;
      float rv = ls_rz[(w * 16 + rl) * 16 + c], zv = ls_rz[(w * 16 + rl) * 16 + 4 + c];
      float gi = ls_gi[(w * 16 + rl) * 8 + c], gh = ls_gh[(w * 16 + rl) * 8 + c];
      float r = 1.f / (1.f + expf(-rv));
      float z = 1.f / (1.f + expf(-zv));
      float n = tanhf(gi + r * gh);
      int b = w * 16 + rl;
      int g2 = hd2 + c;
      float hmnew = (1.f - z) * n + z * hm_reg;
      hm_reg = hmnew;
      int ar = s * 64 + b;    // s-major
      u16 xh, xl; split_bf16(hmnew, xh, xl);
      astore(apk + ar * 256 + g2, (u32)xh | ((u32)xl << 16));
    }
    ++epoch;
    bar_arrive(slots, blk, epoch);

    // ---- pre-poll local work for next step: a2s = Whh @ h_task (regs) ----
    a2s[0] = (f32x4){0.f, 0.f, 0.f, 0.f};
    a2s[1] = (f32x4){0.f, 0.f, 0.f, 0.f};
    if (s < 29) {
      #pragma unroll
      for (int k = 0; k < 8; ++k) {
        #pragma unroll
        for (int nt = 0; nt < 2; ++nt) {
          short8 bh = *(const short8*)(lw1h + ((8 + k) * 2 + nt) * 512 + lane * 8);
          short8 bl = *(const short8*)(lw1l + ((8 + k) * 2 + nt) * 512 + lane * 8);
          a2s[nt] = mfma16(xh2[k], bh, a2s[nt]);
          a2s[nt] = mfma16(xl2[k], bh, a2s[nt]);
          a2s[nt] = mfma16(xh2[k], bl, a2s[nt]);
        }
      }
    }
  }
  // final: publish epoch 60 once all blocks have arrived (gnew q=7 waits on it)
  if (blk == 0) {
    bar_wait(slots, epoch);
    if (tid == 0) astore(hprog, (u32)epoch);
  }
}

extern "C" void kernel_launch(void* const* d_in, const int* in_sizes, int n_in,
                              void* d_out, int out_size, void* d_ws, size_t ws_size,
                              hipStream_t stream) {
  const int* iv = (const int*)d_in[1];
  const int* cv = (const int*)d_in[2];
  const float* emb = (const float*)d_in[3];
  const float* Wih = (const float*)d_in[4];
  const float* Whh = (const float*)d_in[5];
  const float* bih = (const float*)d_in[6];
  const float* bhh = (const float*)d_in[7];
  const float* mWih = (const float*)d_in[8];
  const float* mWhh = (const float*)d_in[9];
  const float* mbih = (const float*)d_in[10];
  const float* mbhh = (const float*)d_in[11];
  const float* Wnew = (const float*)d_in[12];
  const float* bnew = (const float*)d_in[13];
  const float* Wcopy = (const float*)d_in[14];
  const float* bcopy = (const float*)d_in[15];
  float* out = (float*)d_out;
  char* ws = (char*)d_ws;

  size_t o = 0;
  auto take = [&](size_t sz) { size_t r = o; o += sz; return r; };
  size_t BAR = take(512);        // [0..63] rnn flags, [64] hprog (own line)
  size_t CM  = take(15360);
  size_t EBH = take(983040);
  size_t EBL = take(983040);
  size_t HPK = take(4063232);    // packed bf16 hi|lo task-h [31][2][64][256] u32
  size_t APK = take(1966080);    // packed bf16 hi|lo meta-h [30][64][256] u32 (s-major)
  size_t GIX = take(15728640);   // fp32 gi_x [64 blk][30][64][32]
  size_t W1H = take(2621440);
  size_t W1L = take(2621440);
  size_t W2H = take(1572864);
  size_t W2L = take(1572864);
  size_t WNH = take(10289152);
  size_t WNL = take(10289152);
  if (ws_size < o) return;   // insufficient workspace: fail loudly via absmax

  hipFuncSetAttribute(reinterpret_cast<const void*>(k_mega),
                      hipFuncAttributeMaxDynamicSharedMemorySize, RNN_LDS);

  hipMemsetAsync(ws + BAR, 0, 512, stream);

  k_prep<<<5456, 256, 0, stream>>>(iv, emb, (u16*)(ws + EBH), (u16*)(ws + EBL), (float*)(ws + CM),
                                   Wih, Whh, mWih, mWhh, Wnew,
                                   (u16*)(ws + W1H), (u16*)(ws + W1L),
                                   (u16*)(ws + W2H), (u16*)(ws + W2L),
                                   (u16*)(ws + WNH), (u16*)(ws + WNL));
  k_gix<<<64, 256, 0, stream>>>((const u16*)(ws + EBH), (const u16*)(ws + EBL),
                                (const u16*)(ws + W1H), (const u16*)(ws + W1L),
                                bih, bhh, (float*)(ws + GIX));
  k_mega<<<NB_ + NHELP_, 256, RNN_LDS, stream>>>(
      (const u16*)(ws + W1H), (const u16*)(ws + W1L),
      (const u16*)(ws + W2H), (const u16*)(ws + W2L),
      (const float*)(ws + GIX), bhh, mbih, mbhh,
      (const float*)(ws + CM),
      (u32*)(ws + HPK), (u32*)(ws + APK),
      (u32*)(ws + BAR),
      (const u16*)(ws + WNH), (const u16*)(ws + WNL),
      bnew, cv, Wcopy, bcopy, out);
}

// Round 15
// 465.092 us; speedup vs baseline: 1.2906x; 1.2906x over previous
//
#include <hip/hip_runtime.h>

typedef unsigned short u16;
typedef unsigned int u32;
typedef unsigned long long u64;
typedef __attribute__((ext_vector_type(8))) short short8;
typedef __attribute__((ext_vector_type(4))) float f32x4;

#define NB_ 64
#define NHELP_ 5096   // 7*(512 copy + 157 gnew256) + (256 copy + 157 gnew128)

static __device__ __forceinline__ f32x4 mfma16(short8 a, short8 b, f32x4 c) {
  return __builtin_amdgcn_mfma_f32_16x16x32_bf16(a, b, c, 0, 0, 0);
}

// split fp32 -> bf16 hi + bf16 lo  (x ~= hi + lo, residual ~2^-17 * |x|)
static __device__ __forceinline__ void split_bf16(float x, u16& hi, u16& lo) {
  unsigned u = __float_as_uint(x);
  unsigned r = (u + 0x7fffu + ((u >> 16) & 1u)) >> 16;
  hi = (u16)r;
  float fh = __uint_as_float(r << 16);
  float xl = x - fh;
  unsigned ul = __float_as_uint(xl);
  unsigned rl2 = (ul + 0x7fffu + ((ul >> 16) & 1u)) >> 16;
  lo = (u16)rl2;
}

// write-through publication store to the coherence point (proven r1-r13)
static __device__ __forceinline__ void astore(u32* p, u32 v) {
  __hip_atomic_store(p, v, __ATOMIC_RELAXED, __HIP_MEMORY_SCOPE_AGENT);
}
static __device__ __forceinline__ void unpack8(const uint4& a, const uint4& b,
                                               short8& h, short8& l) {
  u32 wb[8] = {a.x, a.y, a.z, a.w, b.x, b.y, b.z, b.w};
  #pragma unroll
  for (int j = 0; j < 8; ++j) {
    h[j] = (short)(wb[j] & 0xffffu);
    l[j] = (short)(wb[j] >> 16);
  }
}
static __device__ __forceinline__ float unpack_hl(u32 pk) {
  return __uint_as_float((pk & 0xffffu) << 16) + __uint_as_float(pk & 0xffff0000u);
}
static __device__ __forceinline__ void vload8(const u32* p, short8& h, short8& l) {
  uint4 a = *(const uint4*)p;
  uint4 b = *(const uint4*)(p + 4);
  unpack8(a, b, h, l);
}

// ---------------- prep: pooling (blocks 0..1919) + weight swizzle (1920..5455) ----------------
__global__ __launch_bounds__(256) void k_prep(const int* __restrict__ iv,
                                              const float* __restrict__ emb,
                                              u16* __restrict__ ebh, u16* __restrict__ ebl,
                                              float* __restrict__ cm,
                                              const float* __restrict__ Wih,
                                              const float* __restrict__ Whh,
                                              const float* __restrict__ mWih,
                                              const float* __restrict__ mWhh,
                                              const float* __restrict__ Wnew,
                                              u16* __restrict__ w1h, u16* __restrict__ w1l,
                                              u16* __restrict__ w2h, u16* __restrict__ w2l,
                                              u16* __restrict__ wnh, u16* __restrict__ wnl) {
  if (blockIdx.x < 1920) {
    int u = blockIdx.x * 2 + (threadIdx.x >> 7);   // u = (s*2+t)*64+b
    int s = u >> 7;
    int t = (u >> 6) & 1;
    int b = u & 63;
    int d = threadIdx.x & 127;
    const int ibase = ((t * 64 + b) * 30 + s) * 12;
    float sum = 0.f;
    int cnt = 0;
    for (int k = 0; k < 12; ++k) {
      int idx = iv[ibase + k];
      if (idx > 0) { cnt++; sum += emb[(size_t)idx * 128 + d]; }
    }
    float den = (cnt > 0) ? (float)cnt : 1.f;
    float v = sum / den;
    u16 hi, lo; split_bf16(v, hi, lo);
    ebh[(size_t)u * 128 + d] = hi;
    ebl[(size_t)u * 128 + d] = lo;
    if (d == 0) cm[u] = (cnt > 0) ? 1.f : 0.f;
    return;
  }
  int gu = (blockIdx.x - 1920) * 4 + (threadIdx.x >> 6);
  int lane = threadIdx.x & 63;
  int ko = (lane >> 4) * 8;
  int cl = lane & 15;
  float src[8];
  if (gu < 2560) {
    int blk = gu / 40, r = gu % 40, ksIdx = r >> 1, nt = r & 1;
    int t = blk >> 5, hd0 = (blk & 31) * 8;
    int c = nt * 16 + cl;
    if (c < 24) {
      int gc = (c < 8) ? (hd0 + c) : (c < 16) ? (256 + hd0 + (c - 8)) : (512 + hd0 + (c - 16));
      const float* wrow; int kk;
      if (ksIdx < 8)       { wrow = Wih + (size_t)(t * 768 + gc) * 384 + 128; kk = ksIdx * 32 + ko; }
      else if (ksIdx < 16) { wrow = Whh + (size_t)(t * 768 + gc) * 256;       kk = (ksIdx - 8) * 32 + ko; }
      else                 { wrow = Wih + (size_t)(t * 768 + gc) * 384;       kk = (ksIdx - 16) * 32 + ko; }
      #pragma unroll
      for (int j = 0; j < 8; ++j) src[j] = wrow[kk + j];
    } else {
      #pragma unroll
      for (int j = 0; j < 8; ++j) src[j] = 0.f;
    }
    int off = gu * 512 + lane * 8;
    #pragma unroll
    for (int j = 0; j < 8; ++j) { u16 h, l; split_bf16(src[j], h, l); w1h[off + j] = h; w1l[off + j] = l; }
  } else if (gu < 4096) {
    int g2 = gu - 2560;
    int blk = g2 / 24, ksIdx = g2 % 24;
    int t1 = blk >> 5;
    int hd0 = blk * 4;
    int c = cl;
    if (c < 12) {
      int gc = (c < 4) ? (hd0 + c) : (c < 8) ? (256 + hd0 + (c - 4)) : (512 + hd0 + (c - 8));
      if (ksIdx < 16) {
        int chunk = (ksIdx < 8) ? (t1 * 8 + ksIdx) : ((1 - t1) * 8 + (ksIdx - 8));
        int kk = chunk * 32 + ko;
        #pragma unroll
        for (int j = 0; j < 8; ++j) src[j] = mWih[(size_t)gc * 512 + kk + j];
      } else {
        int kk = (ksIdx - 16) * 32 + ko;
        #pragma unroll
        for (int j = 0; j < 8; ++j) src[j] = mWhh[(size_t)gc * 256 + kk + j];
      }
    } else {
      #pragma unroll
      for (int j = 0; j < 8; ++j) src[j] = 0.f;
    }
    int off = g2 * 512 + lane * 8;
    #pragma unroll
    for (int j = 0; j < 8; ++j) { u16 h, l; split_bf16(src[j], h, l); w2h[off + j] = h; w2l[off + j] = l; }
  } else if (gu < 14144) {
    int g3 = gu - 4096;
    int gnt = g3 >> 3, ks = g3 & 7;
    int col = gnt * 16 + cl;
    if (col < 20000) {
      int kk = ks * 32 + ko;
      #pragma unroll
      for (int j = 0; j < 8; ++j) src[j] = Wnew[(size_t)col * 256 + kk + j];
    } else {
      #pragma unroll
      for (int j = 0; j < 8; ++j) src[j] = 0.f;
    }
    int off = g3 * 512 + lane * 8;
    #pragma unroll
    for (int j = 0; j < 8; ++j) { u16 h, l; split_bf16(src[j], h, l); wnh[off + j] = h; wnl[off + j] = l; }
  }
}

// ---------------- gi_x precompute: gi_x = x @ WihX^T (+bias folds) ----------------
// layout: gix[blk][s][row 0..63][32]: cols 0..15 = r,z (+bih+bhh), 16..23 = n (+bih)
__global__ __launch_bounds__(256) void k_gix(const u16* __restrict__ ebh, const u16* __restrict__ ebl,
                                             const u16* __restrict__ w1h, const u16* __restrict__ w1l,
                                             const float* __restrict__ bih, const float* __restrict__ bhh,
                                             float* __restrict__ gix) {
  int blk = blockIdx.x;
  int t1 = blk >> 5, hd1 = (blk & 31) * 8;
  int tid = threadIdx.x, lane = tid & 63, w = tid >> 6;
  int arow = w * 16 + (lane & 15);
  int ko = (lane >> 4) * 8;
  __shared__ u16 lwh[4096], lwl[4096];
  {
    const uint4* sh = (const uint4*)(w1h + ((size_t)blk * 40 + 32) * 512);
    const uint4* sl = (const uint4*)(w1l + ((size_t)blk * 40 + 32) * 512);
    uint4* dh = (uint4*)lwh; uint4* dl = (uint4*)lwl;
    for (int i = tid; i < 512; i += 256) { dh[i] = sh[i]; dl[i] = sl[i]; }
  }
  int c = lane & 15;
  float brz, bn = 0.f;
  {
    int gc = (c < 8) ? (hd1 + c) : (256 + hd1 + (c - 8));
    brz = bih[t1 * 768 + gc] + bhh[t1 * 768 + gc];
    if (c < 8) bn = bih[t1 * 768 + 512 + hd1 + c];
  }
  __syncthreads();
  for (int s = 0; s < 30; ++s) {
    f32x4 a3[2];
    a3[0] = (f32x4){0.f, 0.f, 0.f, 0.f};
    a3[1] = (f32x4){0.f, 0.f, 0.f, 0.f};
    const u16* Xh = ebh + (size_t)((s * 2 + t1) * 64 + arow) * 128;
    const u16* Xl = ebl + (size_t)((s * 2 + t1) * 64 + arow) * 128;
    #pragma unroll
    for (int k = 0; k < 4; ++k) {
      short8 xh = *(const short8*)(Xh + k * 32 + ko);
      short8 xl = *(const short8*)(Xl + k * 32 + ko);
      #pragma unroll
      for (int nt = 0; nt < 2; ++nt) {
        short8 bh = *(const short8*)(lwh + (k * 2 + nt) * 512 + lane * 8);
        short8 bl = *(const short8*)(lwl + (k * 2 + nt) * 512 + lane * 8);
        a3[nt] = mfma16(xh, bh, a3[nt]);
        a3[nt] = mfma16(xl, bh, a3[nt]);
        a3[nt] = mfma16(xh, bl, a3[nt]);
      }
    }
    float* grow = gix + (size_t)(blk * 30 + s) * 64 * 32;
    #pragma unroll
    for (int i = 0; i < 4; ++i) {
      int r = w * 16 + (lane >> 4) * 4 + i;
      grow[r * 32 + c] = a3[0][i] + brz;
      if (c < 8) grow[r * 32 + 16 + c] = a3[1][i] + bn;
    }
  }
}

// ---------------- barrier helpers ----------------
static __device__ __forceinline__ void bar_arrive(u32* slots, int blk, int epoch) {
  __syncthreads();              // all waves' publication stores drained
  if (threadIdx.x == 0) astore(slots + blk, (u32)epoch);
}
static __device__ __forceinline__ void bar_wait(u32* slots, int epoch) {
  int lane = threadIdx.x & 63;
  u32 v;
  for (;;) {
    asm volatile("global_load_dword %0, %1, off sc0 sc1\n\ts_waitcnt vmcnt(0)"
                 : "=v"(v) : "v"(slots + lane) : "memory");
    if ((int)v >= epoch) break;
  }
}
// helpers poll ONLY hprog (own cache line, written by rnn block 0)
static __device__ __forceinline__ void helper_wait(const u32* hprog, int target) {
  if (threadIdx.x == 0) {
    u32 v;
    for (;;) {
      asm volatile("global_load_dword %0, %1, off sc0 sc1\n\ts_waitcnt vmcnt(0)"
                   : "=v"(v) : "v"(hprog) : "memory");
      if ((int)v >= target) break;
      __builtin_amdgcn_s_sleep(15);
      __builtin_amdgcn_s_sleep(15);
    }
  }
  __syncthreads();
}

// gnew tile: MI m-subtiles of 16 rows per wave (rows = 64*MI per block)
template<int MI>
static __device__ __forceinline__ void gnew_tile(int rowbase, int nb, int tid,
                                                 const u32* __restrict__ apk,
                                                 const u16* __restrict__ wnh,
                                                 const u16* __restrict__ wnl,
                                                 const float* __restrict__ bnew,
                                                 float* __restrict__ out) {
  int lane = tid & 63, w = tid >> 6;
  int ko = (lane >> 4) * 8;
  f32x4 acc[MI][8];
  #pragma unroll
  for (int mi = 0; mi < MI; ++mi)
    #pragma unroll
    for (int nt = 0; nt < 8; ++nt) acc[mi][nt] = (f32x4){0.f, 0.f, 0.f, 0.f};
  #pragma unroll
  for (int ks = 0; ks < 8; ++ks) {
    short8 ah[MI], al[MI];
    #pragma unroll
    for (int mi = 0; mi < MI; ++mi) {
      int rrow = rowbase + (w * MI + mi) * 16 + (lane & 15);
      vload8(apk + (size_t)rrow * 256 + ks * 32 + ko, ah[mi], al[mi]);
    }
    #pragma unroll
    for (int nt = 0; nt < 8; ++nt) {
      int un = (nb * 8 + nt) * 8 + ks;
      short8 bh = *(const short8*)(wnh + (size_t)un * 512 + lane * 8);
      short8 bl = *(const short8*)(wnl + (size_t)un * 512 + lane * 8);
      #pragma unroll
      for (int mi = 0; mi < MI; ++mi) {
        acc[mi][nt] = mfma16(ah[mi], bh, acc[mi][nt]);
        acc[mi][nt] = mfma16(al[mi], bh, acc[mi][nt]);
        acc[mi][nt] = mfma16(ah[mi], bl, acc[mi][nt]);
      }
    }
  }
  #pragma unroll
  for (int mi = 0; mi < MI; ++mi)
    #pragma unroll
    for (int nt = 0; nt < 8; ++nt) {
      int col = nb * 128 + nt * 16 + (lane & 15);
      if (col < 20000) {
        float bn = bnew[col];
        #pragma unroll
        for (int i = 0; i < 4; ++i) {
          int rrow = rowbase + (w * MI + mi) * 16 + (lane >> 4) * 4 + i;
          int sA = rrow >> 6, bA = rrow & 63;
          out[(size_t)(bA * 30 + sA) * 20000 + col] = acc[mi][nt][i] + bn;
        }
      }
    }
}

// dynamic LDS layout (bytes):
//   [0) w1h 32768 | w1l 32768 | w2h 24576 | w2l 24576 | ls_rz 4096 | ls_gi 2048
//   | ls_gh 2048 | ls_cm 7680 -> total 130560
#define RNN_LDS 130560

// Mega kernel: blocks 0..63 = persistent GRU recurrence (apk s-major);
// helpers ordered by readiness: g=0..6: {512 copy (s=4g..4g+3), 157 gnew256 q=g};
// then {256 copy (s=28,29), 157 gnew128 q=7}.
__global__ __launch_bounds__(256, 1) void k_mega(
    const u16* __restrict__ w1h, const u16* __restrict__ w1l,
    const u16* __restrict__ w2h, const u16* __restrict__ w2l,
    const float* __restrict__ gix,
    const float* __restrict__ bhh,
    const float* __restrict__ mbih, const float* __restrict__ mbhh,
    const float* __restrict__ cm,
    u32* __restrict__ hpk,       // packed (hi|lo<<16) task-h   [31][2][64][256]
    u32* __restrict__ apk,       // packed (hi|lo<<16) meta-h   [30][64][256]  (s-major)
    u32* slots,                  // [0..63] rnn flags; [64] hprog (own line)
    const u16* __restrict__ wnh, const u16* __restrict__ wnl,
    const float* __restrict__ bnew,
    const int* __restrict__ cv,
    const float* __restrict__ wc,
    const float* __restrict__ bc,
    float* __restrict__ out) {
  u32* hprog = slots + 64;

  if (blockIdx.x >= NB_) {
    // ================= helper blocks =================
    int h = blockIdx.x - NB_;
    int tid = threadIdx.x, lane = tid & 63, w = tid >> 6;
    int s = -1, rr = 0, q = -1, nb = 0;
    if (h < 4683) {
      int g = h / 669, r = h % 669;
      if (r < 512) { s = 4 * g + (r >> 7); rr = r & 127; }
      else         { q = g; nb = r - 512; }
    } else {
      int h2 = h - 4683;
      if (h2 < 256) { s = 28 + (h2 >> 7); rr = h2 & 127; }
      else          { q = 7; nb = h2 - 256; }
    }
    if (s >= 0) {
      // ---- copy-score block: zero own row early, wait for hpk[s+1], scatter ----
      int t = rr >> 6, b = rr & 63;
      float* orow = out + (size_t)(1 + t) * 38400000 + (size_t)(b * 30 + s) * 20000;
      f32x4 z4 = {0.f, 0.f, 0.f, 0.f};
      f32x4* zp = (f32x4*)orow;
      for (int i = tid; i < 5000; i += 256)
        __builtin_nontemporal_store(z4, zp + i);
      helper_wait(hprog, 2 * s + 1);   // syncthreads inside drains zero-stores
      const u32* hp = hpk + (size_t)(((s + 1) * 2 + t) * 64 + b) * 256;
      uint4 hq = *(const uint4*)(hp + lane * 4);
      float4 h4;
      h4.x = unpack_hl(hq.x); h4.y = unpack_hl(hq.y);
      h4.z = unpack_hl(hq.z); h4.w = unpack_hl(hq.w);
      int base = ((t * 64 + b) * 30 + s) * 20;
      for (int c = w; c < 20; c += 4) {
        int idx = cv[base + c];
        const float* wr = wc + ((size_t)t * 20000 + idx) * 256;
        float4 w4 = *(const float4*)(wr + lane * 4);
        float d = h4.x * w4.x + h4.y * w4.y + h4.z * w4.z + h4.w * w4.w;
        #pragma unroll
        for (int m = 32; m >= 1; m >>= 1) d += __shfl_xor(d, m, 64);
        if (lane == 0) orow[idx] = d + bc[t * 20000 + idx];
      }
    } else if (q < 7) {
      helper_wait(hprog, 8 * q + 8);   // apk rows s=4q..4q+3 published
      gnew_tile<4>(q * 256, nb, tid, apk, wnh, wnl, bnew, out);
    } else {
      helper_wait(hprog, 60);          // last 128 rows (s=28,29)
      gnew_tile<2>(1792, nb, tid, apk, wnh, wnl, bnew, out);
    }
    return;
  }

  // ================= recurrence blocks (r9/r11 structure) =================
  extern __shared__ char smem[];
  u16* lw1h = (u16*)smem;
  u16* lw1l = (u16*)(smem + 32768);
  u16* lw2h = (u16*)(smem + 65536);
  u16* lw2l = (u16*)(smem + 90112);
  float* ls_rz = (float*)(smem + 114688);
  float* ls_gi = (float*)(smem + 118784);
  float* ls_gh = (float*)(smem + 120832);
  float* ls_cm = (float*)(smem + 122880);

  const int blk = blockIdx.x;
  const int tid = threadIdx.x;
  const int lane = tid & 63;
  const int w = tid >> 6;
  const int t1 = blk >> 5;
  const int hd1 = (blk & 31) * 8;
  const int hd2 = blk * 4;
  const int arow = w * 16 + (lane & 15);
  const int ko = (lane >> 4) * 8;
  int epoch = 0;

  // one-time: weights -> LDS, cm -> LDS
  {
    const uint4* s1h = (const uint4*)(w1h + (size_t)blk * 40 * 512);
    const uint4* s1l = (const uint4*)(w1l + (size_t)blk * 40 * 512);
    uint4* d1h = (uint4*)lw1h; uint4* d1l = (uint4*)lw1l;
    for (int i = tid; i < 2048; i += 256) { d1h[i] = s1h[i]; d1l[i] = s1l[i]; }
    const uint4* s2h = (const uint4*)(w2h + (size_t)blk * 24 * 512);
    const uint4* s2l = (const uint4*)(w2l + (size_t)blk * 24 * 512);
    uint4* d2h = (uint4*)lw2h; uint4* d2l = (uint4*)lw2l;
    for (int i = tid; i < 1536; i += 256) { d2h[i] = s2h[i]; d2l[i] = s2l[i]; }
    for (int i = tid; i < 1920; i += 256) ls_cm[i] = cm[((i >> 6) * 2 + t1) * 64 + (i & 63)];
  }
  // hoisted per-thread constants
  const int cc = lane & 15;
  float bhhn = (cc < 8) ? bhh[t1 * 768 + 512 + hd1 + cc] : 0.f;
  float mrz_b = 0.f, mgi_b = 0.f, mgh_b = 0.f;
  if (cc < 8) {
    int gc = (cc < 4) ? (hd2 + cc) : (256 + hd2 + (cc - 4));
    mrz_b = mbih[gc] + mbhh[gc];
  } else if (cc < 12) {
    int gn = 512 + hd2 + (cc - 8);
    mgi_b = mbih[gn];
    mgh_b = mbhh[gn];
  }

  // gi_x prefetch registers
  float gq[8];
  {
    const float* grow = gix + (size_t)(blk * 30 + 0) * 2048;
    #pragma unroll
    for (int i = 0; i < 4; ++i) {
      int r = w * 16 + (lane >> 4) * 4 + i;
      gq[i]     = grow[r * 32 + cc];
      gq[4 + i] = grow[r * 32 + 16 + (cc & 7)];
    }
  }
  __syncthreads();

  short8 ah1[8], al1[8];   // apk[s-1] (G1; reused by m2)
  short8 xh2[8], xl2[8];   // own-task hpk[s] (loaded phase-2 of s-1; used by a2s)
  f32x4 a2s[2];            // Whh @ h_task, precomputed at end of previous iteration
  a2s[0] = (f32x4){0.f, 0.f, 0.f, 0.f};
  a2s[1] = (f32x4){0.f, 0.f, 0.f, 0.f};
  float hold0 = 0.f, hold1 = 0.f;
  float hm_reg = 0.f;

  for (int s = 0; s < 30; ++s) {
    // ---------- phase 1: task GRUs ----------
    f32x4 a1[2];
    a1[0] = (f32x4){0.f, 0.f, 0.f, 0.f};
    a1[1] = (f32x4){0.f, 0.f, 0.f, 0.f};
    if (s > 0) {
      bar_wait(slots, epoch);
      if (blk == 0 && tid == 0) astore(hprog, (u32)epoch);   // all-arrived(epoch) proven
      const u32* Ap = apk + (size_t)((s - 1) * 64 + arow) * 256 + ko;
      uint4 ra[16];
      #pragma unroll
      for (int k = 0; k < 8; ++k) {
        ra[2 * k]     = *(const uint4*)(Ap + k * 32);
        ra[2 * k + 1] = *(const uint4*)(Ap + k * 32 + 4);
      }
      #pragma unroll
      for (int k = 0; k < 8; ++k) {
        unpack8(ra[2 * k], ra[2 * k + 1], ah1[k], al1[k]);
        #pragma unroll
        for (int nt = 0; nt < 2; ++nt) {
          short8 bh = *(const short8*)(lw1h + (k * 2 + nt) * 512 + lane * 8);
          short8 bl = *(const short8*)(lw1l + (k * 2 + nt) * 512 + lane * 8);
          a1[nt] = mfma16(ah1[k], bh, a1[nt]);
          a1[nt] = mfma16(al1[k], bh, a1[nt]);
          a1[nt] = mfma16(ah1[k], bl, a1[nt]);
        }
      }
    }
    // gates -> LDS (per-wave slices; intra-wave ordering via lgkmcnt)
    #pragma unroll
    for (int i = 0; i < 4; ++i) {
      int rl = (lane >> 4) * 4 + i;
      ls_rz[(w * 16 + rl) * 16 + cc] = a1[0][i] + a2s[0][i] + gq[i];
      if (cc < 8) {
        ls_gi[(w * 16 + rl) * 8 + cc] = a1[1][i] + gq[4 + i];
        ls_gh[(w * 16 + rl) * 8 + cc] = a2s[1][i] + bhhn;
      }
    }
    asm volatile("s_waitcnt lgkmcnt(0)" ::: "memory");
    {
      int item = lane;
      int rl = item >> 3, c = item & 7;
      float rv = ls_rz[(w * 16 + rl) * 16 + c], zv = ls_rz[(w * 16 + rl) * 16 + 8 + c];
      float gi = ls_gi[(w * 16 + rl) * 8 + c], gh = ls_gh[(w * 16 + rl) * 8 + c];
      float r = 1.f / (1.f + expf(-rv));
      float z = 1.f / (1.f + expf(-zv));
      float n = tanhf(gi + r * gh);
      int b = w * 16 + rl;
      float m = ls_cm[s * 64 + b];
      float hnew = (1.f - z) * n + z * hold0;
      float hout = (m > 0.5f) ? hnew : hold0;
      hold0 = hout;
      int oo = (((s + 1) * 2 + t1) * 64 + b) * 256 + hd1 + c;
      u16 xh, xl; split_bf16(hout, xh, xl);
      astore(hpk + oo, (u32)xh | ((u32)xl << 16));
    }
    {
      int item = 64 + lane;
      int rl = item >> 3, c = item & 7;
      float rv = ls_rz[(w * 16 + rl) * 16 + c], zv = ls_rz[(w * 16 + rl) * 16 + 8 + c];
      float gi = ls_gi[(w * 16 + rl) * 8 + c], gh = ls_gh[(w * 16 + rl) * 8 + c];
      float r = 1.f / (1.f + expf(-rv));
      float z = 1.f / (1.f + expf(-zv));
      float n = tanhf(gi + r * gh);
      int b = w * 16 + rl;
      float m = ls_cm[s * 64 + b];
      float hnew = (1.f - z) * n + z * hold1;
      float hout = (m > 0.5f) ? hnew : hold1;
      hold1 = hout;
      int oo = (((s + 1) * 2 + t1) * 64 + b) * 256 + hd1 + c;
      u16 xh, xl; split_bf16(hout, xh, xl);
      astore(hpk + oo, (u32)xh | ((u32)xl << 16));
    }
    ++epoch;
    bar_arrive(slots, blk, epoch);

    // ---- pre-poll local work: m2 (mWhh @ h_meta, regs) + gix prefetch ----
    f32x4 m1 = (f32x4){0.f, 0.f, 0.f, 0.f};
    f32x4 m2 = (f32x4){0.f, 0.f, 0.f, 0.f};
    if (s > 0) {
      #pragma unroll
      for (int k = 0; k < 8; ++k) {
        short8 bh = *(const short8*)(lw2h + (16 + k) * 512 + lane * 8);
        short8 bl = *(const short8*)(lw2l + (16 + k) * 512 + lane * 8);
        m2 = mfma16(ah1[k], bh, m2);
        m2 = mfma16(al1[k], bh, m2);
        m2 = mfma16(ah1[k], bl, m2);
      }
    }
    if (s < 29) {
      const float* grow = gix + (size_t)(blk * 30 + s + 1) * 2048;
      #pragma unroll
      for (int i = 0; i < 4; ++i) {
        int r = w * 16 + (lane >> 4) * 4 + i;
        gq[i]     = grow[r * 32 + cc];
        gq[4 + i] = grow[r * 32 + 16 + (cc & 7)];
      }
    }
    bar_wait(slots, epoch);
    if (blk == 0 && tid == 0) astore(hprog, (u32)epoch);

    // ---------- phase 2: meta GRU ----------
    {
      const u32* Hp = hpk + (size_t)(((s + 1) * 2 + t1) * 64 + arow) * 256 + ko;
      const u32* Hq = hpk + (size_t)(((s + 1) * 2 + (1 - t1)) * 64 + arow) * 256 + ko;
      uint4 rx[16], ry[16];
      #pragma unroll
      for (int k = 0; k < 8; ++k) {
        rx[2 * k]     = *(const uint4*)(Hp + k * 32);
        rx[2 * k + 1] = *(const uint4*)(Hp + k * 32 + 4);
        ry[2 * k]     = *(const uint4*)(Hq + k * 32);
        ry[2 * k + 1] = *(const uint4*)(Hq + k * 32 + 4);
      }
      #pragma unroll
      for (int k = 0; k < 8; ++k) {
        unpack8(rx[2 * k], rx[2 * k + 1], xh2[k], xl2[k]);
        short8 bh = *(const short8*)(lw2h + k * 512 + lane * 8);
        short8 bl = *(const short8*)(lw2l + k * 512 + lane * 8);
        m1 = mfma16(xh2[k], bh, m1);
        m1 = mfma16(xl2[k], bh, m1);
        m1 = mfma16(xh2[k], bl, m1);
      }
      #pragma unroll
      for (int k = 0; k < 8; ++k) {
        short8 yh, yl;
        unpack8(ry[2 * k], ry[2 * k + 1], yh, yl);
        short8 bh = *(const short8*)(lw2h + (8 + k) * 512 + lane * 8);
        short8 bl = *(const short8*)(lw2l + (8 + k) * 512 + lane * 8);
        m1 = mfma16(yh, bh, m1);
        m1 = mfma16(yl, bh, m1);
        m1 = mfma16(yh, bl, m1);
      }
    }
    #pragma unroll
    for (int i = 0; i < 4; ++i) {
      int rl = (lane >> 4) * 4 + i;
      if (cc < 8) {
        ls_rz[(w * 16 + rl) * 16 + cc] = m1[i] + m2[i] + mrz_b;
      } else if (cc < 12) {
        ls_gi[(w * 16 + rl) * 8 + (cc - 8)] = m1[i] + mgi_b;
        ls_gh[(w * 16 + rl) * 8 + (cc - 8)] = m2[i] + mgh_b;
      }
    }
    asm volatile("s_waitcnt lgkmcnt(0)" ::: "memory");
    {
      int rl = lane >> 2, c = lane & 3;
      float rv = ls_rz[(w * 16 + rl) * 16 + c], zv = ls_rz[(w * 16 + rl) * 16 + 4 + c];
      float gi = ls_gi[(w * 16 + rl) * 8 + c], gh = ls_gh[(w * 16 + rl) * 8 + c];
      float r = 1.f / (1.f + expf(-rv));
      float z = 1.f / (1.f + expf(-zv));
      float n = tanhf(gi + r * gh);
      int b = w * 16 + rl;
      int g2 = hd2 + c;
      float hmnew = (1.f - z) * n + z * hm_reg;
      hm_reg = hmnew;
      int ar = s * 64 + b;    // s-major
      u16 xh, xl; split_bf16(hmnew, xh, xl);
      astore(apk + ar * 256 + g2, (u32)xh | ((u32)xl << 16));
    }
    ++epoch;
    bar_arrive(slots, blk, epoch);

    // ---- pre-poll local work for next step: a2s = Whh @ h_task (regs) ----
    a2s[0] = (f32x4){0.f, 0.f, 0.f, 0.f};
    a2s[1] = (f32x4){0.f, 0.f, 0.f, 0.f};
    if (s < 29) {
      #pragma unroll
      for (int k = 0; k < 8; ++k) {
        #pragma unroll
        for (int nt = 0; nt < 2; ++nt) {
          short8 bh = *(const short8*)(lw1h + ((8 + k) * 2 + nt) * 512 + lane * 8);
          short8 bl = *(const short8*)(lw1l + ((8 + k) * 2 + nt) * 512 + lane * 8);
          a2s[nt] = mfma16(xh2[k], bh, a2s[nt]);
          a2s[nt] = mfma16(xl2[k], bh, a2s[nt]);
          a2s[nt] = mfma16(xh2[k], bl, a2s[nt]);
        }
      }
    }
  }
  // final: publish epoch 60 once all blocks have arrived (gnew q=7 waits on it)
  if (blk == 0) {
    bar_wait(slots, epoch);
    if (tid == 0) astore(hprog, (u32)epoch);
  }
}

extern "C" void kernel_launch(void* const* d_in, const int* in_sizes, int n_in,
                              void* d_out, int out_size, void* d_ws, size_t ws_size,
                              hipStream_t stream) {
  const int* iv = (const int*)d_in[1];
  const int* cv = (const int*)d_in[2];
  const float* emb = (const float*)d_in[3];
  const float* Wih = (const float*)d_in[4];
  const float* Whh = (const float*)d_in[5];
  const float* bih = (const float*)d_in[6];
  const float* bhh = (const float*)d_in[7];
  const float* mWih = (const float*)d_in[8];
  const float* mWhh = (const float*)d_in[9];
  const float* mbih = (const float*)d_in[10];
  const float* mbhh = (const float*)d_in[11];
  const float* Wnew = (const float*)d_in[12];
  const float* bnew = (const float*)d_in[13];
  const float* Wcopy = (const float*)d_in[14];
  const float* bcopy = (const float*)d_in[15];
  float* out = (float*)d_out;
  char* ws = (char*)d_ws;

  size_t o = 0;
  auto take = [&](size_t sz) { size_t r = o; o += sz; return r; };
  size_t BAR = take(512);        // [0..63] rnn flags, [64] hprog (own line)
  size_t CM  = take(15360);
  size_t EBH = take(983040);
  size_t EBL = take(983040);
  size_t HPK = take(4063232);    // packed bf16 hi|lo task-h [31][2][64][256] u32
  size_t APK = take(1966080);    // packed bf16 hi|lo meta-h [30][64][256] u32 (s-major)
  size_t GIX = take(15728640);   // fp32 gi_x [64 blk][30][64][32]
  size_t W1H = take(2621440);
  size_t W1L = take(2621440);
  size_t W2H = take(1572864);
  size_t W2L = take(1572864);
  size_t WNH = take(10289152);
  size_t WNL = take(10289152);
  if (ws_size < o) return;   // insufficient workspace: fail loudly via absmax

  hipFuncSetAttribute(reinterpret_cast<const void*>(k_mega),
                      hipFuncAttributeMaxDynamicSharedMemorySize, RNN_LDS);

  hipMemsetAsync(ws + BAR, 0, 512, stream);

  k_prep<<<5456, 256, 0, stream>>>(iv, emb, (u16*)(ws + EBH), (u16*)(ws + EBL), (float*)(ws + CM),
                                   Wih, Whh, mWih, mWhh, Wnew,
                                   (u16*)(ws + W1H), (u16*)(ws + W1L),
                                   (u16*)(ws + W2H), (u16*)(ws + W2L),
                                   (u16*)(ws + WNH), (u16*)(ws + WNL));
  k_gix<<<64, 256, 0, stream>>>((const u16*)(ws + EBH), (const u16*)(ws + EBL),
                                (const u16*)(ws + W1H), (const u16*)(ws + W1L),
                                bih, bhh, (float*)(ws + GIX));
  k_mega<<<NB_ + NHELP_, 256, RNN_LDS, stream>>>(
      (const u16*)(ws + W1H), (const u16*)(ws + W1L),
      (const u16*)(ws + W2H), (const u16*)(ws + W2L),
      (const float*)(ws + GIX), bhh, mbih, mbhh,
      (const float*)(ws + CM),
      (u32*)(ws + HPK), (u32*)(ws + APK),
      (u32*)(ws + BAR),
      (const u16*)(ws + WNH), (const u16*)(ws + WNL),
      bnew, cv, Wcopy, bcopy, out);
}